// Round 15
// baseline (91.903 us; speedup 1.0000x reference)
//
#include <hip/hip_runtime.h>

// GCN: out = agg(relu(agg(F)@W1 + b1)) @ W2 + b2
// Reordered (agg linear): P1 = F@W1 (bf16); A1 = b1 + agg(P1); P2 = relu(A1)@W2 (bf16);
//                         out = b2 + agg(P2)
// r14 skeleton; ONE change family (bisection): aggs process 4 nodes/wave (16/block).
//   - W2 LDS restage amortized 4x (was 8KB per 4 nodes = 40MB total, > gather payload)
//   - 4 nodes' cnt loads + slot prefetches issued UPFRONT as independent streams
//   - grid 5000 -> 1256 blocks; per-wave work 4x (latency amortization)
//   fill2: FILL_BPG 80 -> 160 (2x scatter parallelism).
// Lessons kept: no grid.sync (r7), no per-window compaction (r8), XCD-local slot
// writes (r4), ballot histogram (r10), shfl outside divergent guards (r13),
// coalesced LDS-staged F (r14), static unroll only (no runtime-indexed arrays).

#define NF 128
#define H1 64
#define H2 32
#define CAP 128       // slot capacity/node; deg ~ Poisson(32), P(>128) ~ 1e-30; guarded
#define CAPSH 7
#define NG8 8         // node-range groups (== XCDs)
#define SCHUNK 1024   // edges per stage block
#define FILL_BPG 160  // fill2 blocks per group

__device__ __forceinline__ float blo(unsigned u){ return __uint_as_float(u << 16); }
__device__ __forceinline__ float bhi(unsigned u){ return __uint_as_float(u & 0xffff0000u); }
__device__ __forceinline__ unsigned short f2b(float f){   // fp32 -> bf16 RNE
    unsigned x = __float_as_uint(f);
    return (unsigned short)((x + 0x7fffu + ((x >> 16) & 1u)) >> 16);
}

// ---- K1: stage blocks (bid < nsb) + gemm1 blocks (bid >= nsb) ---- (r14 verbatim)
__launch_bounds__(256)
__global__ void k1_kernel(const float* __restrict__ F, const float* __restrict__ W1,
                          const int* __restrict__ src, const int* __restrict__ dst,
                          unsigned* __restrict__ staged, int* __restrict__ bofs,
                          unsigned short* __restrict__ P1b, int* __restrict__ cnt,
                          unsigned inv_sz, int n_nodes, int n_edges, int nsb) {
    __shared__ __align__(16) float shbuf[4][8][NF];   // 16 KB: frow (gemm) / sorted (stage)
    __shared__ int wcnt[4][NG8];
    __shared__ int wbase[4][NG8];
    __shared__ int bb0[NG8 + 1];
    const int t = threadIdx.x;
    const int bid = blockIdx.x;
    const int wid = t >> 6, lane = t & 63;

    if (bid < nsb) {
        // ---------- stage role: sort 1024-edge chunk by XCD-group bucket ----------
        unsigned* sorted = (unsigned*)&shbuf[0][0][0];     // first 4 KB
        int e0 = bid * SCHUNK;
        int ce = min(n_edges - e0, SCHUNK);
        int i4 = e0 + t * 4;
        int dd[4], ss[4], bb[4], pp[4];
        bool val[4];
        if (i4 + 4 <= n_edges) {
            int4 d4 = *(const int4*)(dst + i4);
            int4 s4 = *(const int4*)(src + i4);
            dd[0]=d4.x; dd[1]=d4.y; dd[2]=d4.z; dd[3]=d4.w;
            ss[0]=s4.x; ss[1]=s4.y; ss[2]=s4.z; ss[3]=s4.w;
        } else {
#pragma unroll
            for (int k = 0; k < 4; ++k) {
                int e = i4 + k;
                dd[k] = (e < n_edges) ? dst[e] : -1;
                ss[k] = (e < n_edges) ? src[e] : 0;
            }
        }
        unsigned long long lt = (1ULL << lane) - 1ULL;
#pragma unroll
        for (int k = 0; k < 4; ++k) {
            val[k] = dd[k] >= 0;
            bb[k] = val[k]
                ? (int)(unsigned)(((unsigned long long)(unsigned)dd[k] * inv_sz) >> 32)
                : 0;
        }
#pragma unroll
        for (int b = 0; b < NG8; ++b) {
            int running = 0;
#pragma unroll
            for (int k = 0; k < 4; ++k) {
                unsigned long long m = __ballot(val[k] && (bb[k] == b));
                if (val[k] && (bb[k] == b)) pp[k] = running + (int)__popcll(m & lt);
                running += (int)__popcll(m);
            }
            if (lane == 0) wcnt[wid][b] = running;
        }
        __syncthreads();
        if (t < NG8) {
            int tot = 0;
#pragma unroll
            for (int w = 0; w < 4; ++w) { wbase[w][t] = tot; tot += wcnt[w][t]; }
            bb0[t] = tot;
        }
        __syncthreads();
        if (t == 0) {
            int run = 0;
#pragma unroll
            for (int b = 0; b < NG8; ++b) { int c = bb0[b]; bb0[b] = run; run += c; }
            bb0[NG8] = run;
        }
        __syncthreads();
#pragma unroll
        for (int k = 0; k < 4; ++k)
            if (val[k])
                sorted[bb0[bb[k]] + wbase[wid][bb[k]] + pp[k]] =
                    ((unsigned)dd[k] << 16) | (unsigned)ss[k];
        __syncthreads();
        for (int j = t; j < ce; j += 256) staged[(size_t)bid * SCHUNK + j] = sorted[j];
        if (t < NG8 + 1) bofs[t * nsb + bid] = bb0[t];
        return;
    }

    // ---------- gemm1 role: zero cnt; P1b = F @ W1 (F via LDS stage, W1 in VGPRs) ----
    int gb = bid - nsb;
    int zi = gb * 256 + t;
    if (zi < n_nodes) cnt[zi] = 0;
    int row0 = gb * 32 + wid * 8;
    {
        const float4* F4 = (const float4*)F;              // row stride = 32 float4
        float4 tmp[4];
#pragma unroll
        for (int j = 0; j < 4; ++j) {
            int flat = j * 64 + lane;
            int r = flat >> 5, c4 = flat & 31;
            int row = row0 + r;
            int rc = min(row, n_nodes - 1);               // clamp reads; stores guarded
            tmp[j] = F4[(size_t)rc * 32 + c4];
        }
#pragma unroll
        for (int j = 0; j < 4; ++j) {
            int flat = j * 64 + lane;
            int r = flat >> 5, c4 = flat & 31;
            *(float4*)&shbuf[wid][r][c4 * 4] = tmp[j];
        }
    }
    float acc[8] = {0.f, 0.f, 0.f, 0.f, 0.f, 0.f, 0.f, 0.f};
#pragma unroll 1
    for (int cc = 0; cc < 2; ++cc) {             // two 64-k chunks (caps VGPR use)
        float wreg[64];                          // my column's 64 weights, in registers
#pragma unroll
        for (int k = 0; k < 64; ++k) wreg[k] = W1[(cc * 64 + k) * H1 + lane];
#pragma unroll
        for (int r = 0; r < 8; ++r) {
            const float4* fr = (const float4*)&shbuf[wid][r][cc * 64];
#pragma unroll
            for (int k4 = 0; k4 < 16; ++k4) {
                float4 fv = fr[k4];              // LDS broadcast read (same addr/wave)
                acc[r] += fv.x * wreg[k4 * 4 + 0] + fv.y * wreg[k4 * 4 + 1]
                        + fv.z * wreg[k4 * 4 + 2] + fv.w * wreg[k4 * 4 + 3];
            }
        }
    }
#pragma unroll
    for (int r = 0; r < 8; ++r) {
        int row = row0 + r;
        if (row < n_nodes) P1b[(size_t)row * H1 + lane] = f2b(acc[r]);
    }
}

// ---- K2: fill2 (r13 logic; FILL_BPG doubled) ----
__launch_bounds__(256)
__global__ void fill2_kernel(const unsigned* __restrict__ staged, const int* __restrict__ bofs,
                             int* __restrict__ cnt, unsigned short* __restrict__ slots,
                             int nsb) {
    int g = blockIdx.x & (NG8 - 1), gi = blockIdx.x >> 3;
    for (int sb = gi; sb < nsb; sb += FILL_BPG) {
        int st = bofs[g * nsb + sb];
        int en = bofs[(g + 1) * nsb + sb];
        const unsigned* seg = staged + (size_t)sb * SCHUNK;
        for (int j = st + threadIdx.x; j < en; j += 256) {
            unsigned u = seg[j];
            int d = u >> 16;
            int p = atomicAdd(&cnt[d], 1);
            if (p < CAP) slots[(d << CAPSH) + p] = (unsigned short)(u & 0xffffu);
        }
    }
}

// ---- K3: agg1 + bias + relu + gemm2 -> P2b. 4 nodes/wave (16/block); per-node
// quarter-wave-per-edge shfl-prefetch gathers (r13-proven); upfront cnt+slot loads. ----
__launch_bounds__(256)
__global__ void agg1gemm2_kernel(const unsigned short* __restrict__ P1b,
                                 const int* __restrict__ cnt, const unsigned short* __restrict__ slots,
                                 const float* __restrict__ b1, const float* __restrict__ W2,
                                 unsigned short* __restrict__ P2b, int n_nodes, int sz) {
    __shared__ float w2s[H1 * H2];   // 8 KB
    __shared__ float arow[4][H1];    // 1 KB
    {
        const float4* w4 = (const float4*)W2;
        float4* ws4 = (float4*)w2s;
#pragma unroll
        for (int j = 0; j < 2; ++j) ws4[threadIdx.x + 256 * j] = w4[threadIdx.x + 256 * j];
    }
    __syncthreads();
    int wid = threadIdx.x >> 6, lane = threadIdx.x & 63;
    int g = blockIdx.x & (NG8 - 1), gi = blockIdx.x >> 3;
    int q = lane >> 4, c = lane & 15;
    const uint2* P1v = (const uint2*)P1b;             // row = 16 uint2 (64 bf16)
    int nbase = gi * 16 + wid * 4;                    // node-in-group base for this wave

    // upfront, independent: 4 cnt loads then 4 slot-prefetch loads
    int degs[4], bases[4], myss[4];
#pragma unroll
    for (int u = 0; u < 4; ++u) {
        int ni = nbase + u;
        int node = g * sz + ni;
        bool ok = (ni < sz) && (node < n_nodes);
        int node_c = ok ? node : g * sz;              // clamp loads; stores guarded
        degs[u] = ok ? min(cnt[node_c], CAP) : 0;
        bases[u] = node_c << CAPSH;
    }
#pragma unroll
    for (int u = 0; u < 4; ++u)
        myss[u] = (lane < degs[u]) ? (int)slots[bases[u] + lane] : 0;

#pragma unroll
    for (int u = 0; u < 4; ++u) {
        int ni = nbase + u;
        int node = g * sz + ni;
        bool ok = (ni < sz) && (node < n_nodes);      // wave-uniform
        int deg = degs[u], base = bases[u], mys = myss[u];
        int dmain = min(deg, 64);
        float a0=0.f,a1=0.f,a2=0.f,a3=0.f, b0=0.f,b1v=0.f,b2v=0.f,b3=0.f;
        float c0=0.f,c1=0.f,c2=0.f,c3=0.f, d0=0.f,d1=0.f,d2=0.f,d3=0.f;
        int i = 0;
        for (; i + 16 <= dmain; i += 16) {            // full wave active: shfl safe
            int sA = __shfl(mys, i + q, 64);
            int sB = __shfl(mys, i + 4 + q, 64);
            int sC = __shfl(mys, i + 8 + q, 64);
            int sD = __shfl(mys, i + 12 + q, 64);
            uint2 uA = P1v[(sA << 4) + c];
            uint2 uB = P1v[(sB << 4) + c];
            uint2 uC = P1v[(sC << 4) + c];
            uint2 uD = P1v[(sD << 4) + c];
            a0 += blo(uA.x); a1 += bhi(uA.x); a2 += blo(uA.y); a3 += bhi(uA.y);
            b0 += blo(uB.x); b1v += bhi(uB.x); b2v += blo(uB.y); b3 += bhi(uB.y);
            c0 += blo(uC.x); c1 += bhi(uC.x); c2 += blo(uC.y); c3 += bhi(uC.y);
            d0 += blo(uD.x); d1 += bhi(uD.x); d2 += blo(uD.y); d3 += bhi(uD.y);
        }
        for (; i + 4 <= dmain; i += 4) {              // full wave active: shfl safe
            int sA = __shfl(mys, i + q, 64);
            uint2 uA = P1v[(sA << 4) + c];
            a0 += blo(uA.x); a1 += bhi(uA.x); a2 += blo(uA.y); a3 += bhi(uA.y);
        }
        {   // partial last group: shfl HOISTED above the divergent guard
            int sA = __shfl(mys, i + q, 64);
            if (q < dmain - i) {
                uint2 uA = P1v[(sA << 4) + c];
                a0 += blo(uA.x); a1 += bhi(uA.x); a2 += blo(uA.y); a3 += bhi(uA.y);
            }
        }
        for (int j = 64 + q; j < deg; j += 4) {       // rare deg>64 tail, direct loads
            int sA = slots[base + j];
            uint2 uA = P1v[(sA << 4) + c];
            a0 += blo(uA.x); a1 += bhi(uA.x); a2 += blo(uA.y); a3 += bhi(uA.y);
        }
        a0 += b0 + c0 + d0; a1 += b1v + c1 + d1; a2 += b2v + c2 + d2; a3 += b3 + c3 + d3;
        a0 += __shfl_xor(a0, 16, 64); a0 += __shfl_xor(a0, 32, 64);
        a1 += __shfl_xor(a1, 16, 64); a1 += __shfl_xor(a1, 32, 64);
        a2 += __shfl_xor(a2, 16, 64); a2 += __shfl_xor(a2, 32, 64);
        a3 += __shfl_xor(a3, 16, 64); a3 += __shfl_xor(a3, 32, 64);
        if (q == 0) {
            float4 bb = *(const float4*)(b1 + 4 * c);
            float4 v;
            v.x = fmaxf(a0 + bb.x, 0.f);
            v.y = fmaxf(a1 + bb.y, 0.f);
            v.z = fmaxf(a2 + bb.z, 0.f);
            v.w = fmaxf(a3 + bb.w, 0.f);
            *(float4*)&arow[wid][4 * c] = v;
        }
        // wave-local LDS bounce (in-order within wave)
        int half = lane >> 5, c32 = lane & 31, kb = half * 32;
        float acc2 = 0.f;
#pragma unroll
        for (int k = 0; k < 32; ++k) acc2 += arow[wid][kb + k] * w2s[(kb + k) * H2 + c32];
        acc2 += __shfl_xor(acc2, 32, 64);
        if (ok && lane < 32) P2b[(size_t)node * H2 + c32] = f2b(acc2);
    }
}

// ---- K4: agg2 + bias -> out. 4 nodes/wave (16/block); eighth-wave per edge. ----
__launch_bounds__(256)
__global__ void agg2_kernel(const unsigned short* __restrict__ P2b,
                            const int* __restrict__ cnt, const unsigned short* __restrict__ slots,
                            const float* __restrict__ b2, float* __restrict__ out,
                            int n_nodes, int sz) {
    int wid = threadIdx.x >> 6, lane = threadIdx.x & 63;
    int g = blockIdx.x & (NG8 - 1), gi = blockIdx.x >> 3;
    int o = lane >> 3, c = lane & 7;
    const uint2* P2v = (const uint2*)P2b;             // row = 8 uint2 (32 bf16)
    int nbase = gi * 16 + wid * 4;

    int degs[4], bases[4], myss[4];
#pragma unroll
    for (int u = 0; u < 4; ++u) {
        int ni = nbase + u;
        int node = g * sz + ni;
        bool ok = (ni < sz) && (node < n_nodes);
        int node_c = ok ? node : g * sz;
        degs[u] = ok ? min(cnt[node_c], CAP) : 0;
        bases[u] = node_c << CAPSH;
    }
#pragma unroll
    for (int u = 0; u < 4; ++u)
        myss[u] = (lane < degs[u]) ? (int)slots[bases[u] + lane] : 0;

#pragma unroll
    for (int u = 0; u < 4; ++u) {
        int ni = nbase + u;
        int node = g * sz + ni;
        bool ok = (ni < sz) && (node < n_nodes);      // wave-uniform
        int deg = degs[u], base = bases[u], mys = myss[u];
        int dmain = min(deg, 64);
        float a0=0.f,a1=0.f,a2=0.f,a3=0.f, b0=0.f,b1v=0.f,b2v=0.f,b3=0.f;
        float c0=0.f,c1=0.f,c2=0.f,c3=0.f, d0=0.f,d1=0.f,d2=0.f,d3=0.f;
        int i = 0;
        for (; i + 32 <= dmain; i += 32) {            // full wave active: shfl safe
            int sA = __shfl(mys, i + o, 64);
            int sB = __shfl(mys, i + 8 + o, 64);
            int sC = __shfl(mys, i + 16 + o, 64);
            int sD = __shfl(mys, i + 24 + o, 64);
            uint2 uA = P2v[(sA << 3) + c];
            uint2 uB = P2v[(sB << 3) + c];
            uint2 uC = P2v[(sC << 3) + c];
            uint2 uD = P2v[(sD << 3) + c];
            a0 += blo(uA.x); a1 += bhi(uA.x); a2 += blo(uA.y); a3 += bhi(uA.y);
            b0 += blo(uB.x); b1v += bhi(uB.x); b2v += blo(uB.y); b3 += bhi(uB.y);
            c0 += blo(uC.x); c1 += bhi(uC.x); c2 += blo(uC.y); c3 += bhi(uC.y);
            d0 += blo(uD.x); d1 += bhi(uD.x); d2 += blo(uD.y); d3 += bhi(uD.y);
        }
        for (; i + 8 <= dmain; i += 8) {              // full wave active: shfl safe
            int sA = __shfl(mys, i + o, 64);
            uint2 uA = P2v[(sA << 3) + c];
            a0 += blo(uA.x); a1 += bhi(uA.x); a2 += blo(uA.y); a3 += bhi(uA.y);
        }
        {   // partial last group: shfl HOISTED above the divergent guard
            int sA = __shfl(mys, i + o, 64);
            if (o < dmain - i) {
                uint2 uA = P2v[(sA << 3) + c];
                a0 += blo(uA.x); a1 += bhi(uA.x); a2 += blo(uA.y); a3 += bhi(uA.y);
            }
        }
        for (int j = 64 + o; j < deg; j += 8) {       // rare deg>64 tail
            int sA = slots[base + j];
            uint2 uA = P2v[(sA << 3) + c];
            a0 += blo(uA.x); a1 += bhi(uA.x); a2 += blo(uA.y); a3 += bhi(uA.y);
        }
        a0 += b0 + c0 + d0; a1 += b1v + c1 + d1; a2 += b2v + c2 + d2; a3 += b3 + c3 + d3;
        a0 += __shfl_xor(a0, 8, 64); a0 += __shfl_xor(a0, 16, 64); a0 += __shfl_xor(a0, 32, 64);
        a1 += __shfl_xor(a1, 8, 64); a1 += __shfl_xor(a1, 16, 64); a1 += __shfl_xor(a1, 32, 64);
        a2 += __shfl_xor(a2, 8, 64); a2 += __shfl_xor(a2, 16, 64); a2 += __shfl_xor(a2, 32, 64);
        a3 += __shfl_xor(a3, 8, 64); a3 += __shfl_xor(a3, 16, 64); a3 += __shfl_xor(a3, 32, 64);
        if (ok && o == 0) {
            float4 bb = *(const float4*)(b2 + 4 * c);
            float4 v;
            v.x = a0 + bb.x; v.y = a1 + bb.y; v.z = a2 + bb.z; v.w = a3 + bb.w;
            *(float4*)(out + (size_t)node * H2 + 4 * c) = v;
        }
    }
}

extern "C" void kernel_launch(void* const* d_in, const int* in_sizes, int n_in,
                              void* d_out, int out_size, void* d_ws, size_t ws_size,
                              hipStream_t stream) {
    const float* F  = (const float*)d_in[0];
    const float* W1 = (const float*)d_in[1];
    const float* b1 = (const float*)d_in[2];
    const float* W2 = (const float*)d_in[3];
    const float* b2 = (const float*)d_in[4];
    const int* src  = (const int*)d_in[5];
    const int* dst  = (const int*)d_in[6];
    float* out = (float*)d_out;

    int n_nodes = in_sizes[0] / NF;                       // 20000
    int n_edges = in_sizes[5];                            // 640000
    int sz = (n_nodes + NG8 - 1) / NG8;                   // nodes per group (2500)
    unsigned inv_sz = (unsigned)(((1ULL << 32) + sz - 1) / (unsigned)sz);
    int nsb = (n_edges + SCHUNK - 1) / SCHUNK;            // stage blocks (625)

    // Workspace layout (~11.6 MB):
    unsigned short* P1b = (unsigned short*)d_ws;              // [n][64] bf16   2.56 MB
    unsigned short* P2b = P1b + (size_t)n_nodes * H1;         // [n][32] bf16   1.28 MB
    unsigned short* slots = P2b + (size_t)n_nodes * H2;       // [n][CAP]       5.12 MB
    int* cnt = (int*)(slots + ((size_t)n_nodes << CAPSH));    // [n]            80 KB
    unsigned* staged = (unsigned*)(cnt + n_nodes);            // [nsb][1024]    2.56 MB
    int* bofs = (int*)(staged + (size_t)nsb * SCHUNK);        // [9][nsb]       22.5 KB

    int g1 = nsb + (n_nodes + 31) / 32;                       // 625 + 625
    k1_kernel<<<g1, 256, 0, stream>>>(F, W1, src, dst, staged, bofs, P1b, cnt,
                                      inv_sz, n_nodes, n_edges, nsb);
    fill2_kernel<<<FILL_BPG * NG8, 256, 0, stream>>>(staged, bofs, cnt, slots, nsb);
    int bpg = (sz + 15) / 16;                                 // 16 nodes per block
    agg1gemm2_kernel<<<bpg * NG8, 256, 0, stream>>>(P1b, cnt, slots, b1, W2, P2b, n_nodes, sz);
    agg2_kernel<<<bpg * NG8, 256, 0, stream>>>(P2b, cnt, slots, b2, out, n_nodes, sz);
}

// Round 16
// 82.475 us; speedup vs baseline: 1.1143x; 1.1143x over previous
//
#include <hip/hip_runtime.h>

// GCN: out = agg(relu(agg(F)@W1 + b1)) @ W2 + b2
// Reordered (agg linear): P1 = F@W1 (bf16); A1 = b1 + agg(P1); P2 = relu(A1)@W2 (bf16);
//                         out = b2 + agg(P2)
// r14 VERBATIM (best: 81.5us) + ONE delta: FILL_BPG 80 -> 160 (fill2 scatter TLP 2x;
// correctness-proven inside r15's bundle).
// r15 lesson: aggs hide gather latency via TLP across blocks, NOT per-wave ILP —
// 4-nodes/wave shrank the grid 4x and regressed 10us. 1 node/wave + max grid wins.
// Lessons kept: no grid.sync (r7), no per-window compaction (r8), XCD-local slot
// writes (r4), ballot histogram (r10), shfl outside divergent guards (r13),
// coalesced LDS-staged F (r14).

#define NF 128
#define H1 64
#define H2 32
#define CAP 128       // slot capacity/node; deg ~ Poisson(32), P(>128) ~ 1e-30; guarded
#define CAPSH 7
#define NG8 8         // node-range groups (== XCDs)
#define SCHUNK 1024   // edges per stage block
#define FILL_BPG 160  // fill2 blocks per group (the round-16 delta)

__device__ __forceinline__ float blo(unsigned u){ return __uint_as_float(u << 16); }
__device__ __forceinline__ float bhi(unsigned u){ return __uint_as_float(u & 0xffff0000u); }
__device__ __forceinline__ unsigned short f2b(float f){   // fp32 -> bf16 RNE
    unsigned x = __float_as_uint(f);
    return (unsigned short)((x + 0x7fffu + ((x >> 16) & 1u)) >> 16);
}

// ---- K1: stage blocks (bid < nsb) + gemm1 blocks (bid >= nsb) ---- (r14 verbatim)
__launch_bounds__(256)
__global__ void k1_kernel(const float* __restrict__ F, const float* __restrict__ W1,
                          const int* __restrict__ src, const int* __restrict__ dst,
                          unsigned* __restrict__ staged, int* __restrict__ bofs,
                          unsigned short* __restrict__ P1b, int* __restrict__ cnt,
                          unsigned inv_sz, int n_nodes, int n_edges, int nsb) {
    __shared__ __align__(16) float shbuf[4][8][NF];   // 16 KB: frow (gemm) / sorted (stage)
    __shared__ int wcnt[4][NG8];
    __shared__ int wbase[4][NG8];
    __shared__ int bb0[NG8 + 1];
    const int t = threadIdx.x;
    const int bid = blockIdx.x;
    const int wid = t >> 6, lane = t & 63;

    if (bid < nsb) {
        // ---------- stage role: sort 1024-edge chunk by XCD-group bucket ----------
        unsigned* sorted = (unsigned*)&shbuf[0][0][0];     // first 4 KB
        int e0 = bid * SCHUNK;
        int ce = min(n_edges - e0, SCHUNK);
        int i4 = e0 + t * 4;
        int dd[4], ss[4], bb[4], pp[4];
        bool val[4];
        if (i4 + 4 <= n_edges) {
            int4 d4 = *(const int4*)(dst + i4);
            int4 s4 = *(const int4*)(src + i4);
            dd[0]=d4.x; dd[1]=d4.y; dd[2]=d4.z; dd[3]=d4.w;
            ss[0]=s4.x; ss[1]=s4.y; ss[2]=s4.z; ss[3]=s4.w;
        } else {
#pragma unroll
            for (int k = 0; k < 4; ++k) {
                int e = i4 + k;
                dd[k] = (e < n_edges) ? dst[e] : -1;
                ss[k] = (e < n_edges) ? src[e] : 0;
            }
        }
        unsigned long long lt = (1ULL << lane) - 1ULL;
#pragma unroll
        for (int k = 0; k < 4; ++k) {
            val[k] = dd[k] >= 0;
            bb[k] = val[k]
                ? (int)(unsigned)(((unsigned long long)(unsigned)dd[k] * inv_sz) >> 32)
                : 0;
        }
#pragma unroll
        for (int b = 0; b < NG8; ++b) {
            int running = 0;
#pragma unroll
            for (int k = 0; k < 4; ++k) {
                unsigned long long m = __ballot(val[k] && (bb[k] == b));
                if (val[k] && (bb[k] == b)) pp[k] = running + (int)__popcll(m & lt);
                running += (int)__popcll(m);
            }
            if (lane == 0) wcnt[wid][b] = running;
        }
        __syncthreads();
        if (t < NG8) {
            int tot = 0;
#pragma unroll
            for (int w = 0; w < 4; ++w) { wbase[w][t] = tot; tot += wcnt[w][t]; }
            bb0[t] = tot;
        }
        __syncthreads();
        if (t == 0) {
            int run = 0;
#pragma unroll
            for (int b = 0; b < NG8; ++b) { int c = bb0[b]; bb0[b] = run; run += c; }
            bb0[NG8] = run;
        }
        __syncthreads();
#pragma unroll
        for (int k = 0; k < 4; ++k)
            if (val[k])
                sorted[bb0[bb[k]] + wbase[wid][bb[k]] + pp[k]] =
                    ((unsigned)dd[k] << 16) | (unsigned)ss[k];
        __syncthreads();
        for (int j = t; j < ce; j += 256) staged[(size_t)bid * SCHUNK + j] = sorted[j];
        if (t < NG8 + 1) bofs[t * nsb + bid] = bb0[t];
        return;
    }

    // ---------- gemm1 role: zero cnt; P1b = F @ W1 (F via LDS stage, W1 in VGPRs) ----
    int gb = bid - nsb;
    int zi = gb * 256 + t;
    if (zi < n_nodes) cnt[zi] = 0;
    int row0 = gb * 32 + wid * 8;
    {
        const float4* F4 = (const float4*)F;              // row stride = 32 float4
        float4 tmp[4];
#pragma unroll
        for (int j = 0; j < 4; ++j) {
            int flat = j * 64 + lane;
            int r = flat >> 5, c4 = flat & 31;
            int row = row0 + r;
            int rc = min(row, n_nodes - 1);               // clamp reads; stores guarded
            tmp[j] = F4[(size_t)rc * 32 + c4];
        }
#pragma unroll
        for (int j = 0; j < 4; ++j) {
            int flat = j * 64 + lane;
            int r = flat >> 5, c4 = flat & 31;
            *(float4*)&shbuf[wid][r][c4 * 4] = tmp[j];
        }
    }
    float acc[8] = {0.f, 0.f, 0.f, 0.f, 0.f, 0.f, 0.f, 0.f};
#pragma unroll 1
    for (int cc = 0; cc < 2; ++cc) {             // two 64-k chunks (caps VGPR use)
        float wreg[64];                          // my column's 64 weights, in registers
#pragma unroll
        for (int k = 0; k < 64; ++k) wreg[k] = W1[(cc * 64 + k) * H1 + lane];
#pragma unroll
        for (int r = 0; r < 8; ++r) {
            const float4* fr = (const float4*)&shbuf[wid][r][cc * 64];
#pragma unroll
            for (int k4 = 0; k4 < 16; ++k4) {
                float4 fv = fr[k4];              // LDS broadcast read (same addr/wave)
                acc[r] += fv.x * wreg[k4 * 4 + 0] + fv.y * wreg[k4 * 4 + 1]
                        + fv.z * wreg[k4 * 4 + 2] + fv.w * wreg[k4 * 4 + 3];
            }
        }
    }
#pragma unroll
    for (int r = 0; r < 8; ++r) {
        int row = row0 + r;
        if (row < n_nodes) P1b[(size_t)row * H1 + lane] = f2b(acc[r]);
    }
}

// ---- K2: fill2 (r13 logic; FILL_BPG = 160) ----
__launch_bounds__(256)
__global__ void fill2_kernel(const unsigned* __restrict__ staged, const int* __restrict__ bofs,
                             int* __restrict__ cnt, unsigned short* __restrict__ slots,
                             int nsb) {
    int g = blockIdx.x & (NG8 - 1), gi = blockIdx.x >> 3;
    for (int sb = gi; sb < nsb; sb += FILL_BPG) {
        int st = bofs[g * nsb + sb];
        int en = bofs[(g + 1) * nsb + sb];
        const unsigned* seg = staged + (size_t)sb * SCHUNK;
        for (int j = st + threadIdx.x; j < en; j += 256) {
            unsigned u = seg[j];
            int d = u >> 16;
            int p = atomicAdd(&cnt[d], 1);
            if (p < CAP) slots[(d << CAPSH) + p] = (unsigned short)(u & 0xffffu);
        }
    }
}

// ---- K3: agg1 + bias + relu + gemm2 -> P2b (r14 verbatim: 1 node/wave) ----
__launch_bounds__(256)
__global__ void agg1gemm2_kernel(const unsigned short* __restrict__ P1b,
                                 const int* __restrict__ cnt, const unsigned short* __restrict__ slots,
                                 const float* __restrict__ b1, const float* __restrict__ W2,
                                 unsigned short* __restrict__ P2b, int n_nodes, int sz) {
    __shared__ float w2s[H1 * H2];   // 8 KB
    __shared__ float arow[4][H1];    // 1 KB
    {
        const float4* w4 = (const float4*)W2;
        float4* ws4 = (float4*)w2s;
#pragma unroll
        for (int j = 0; j < 2; ++j) ws4[threadIdx.x + 256 * j] = w4[threadIdx.x + 256 * j];
    }
    __syncthreads();
    int wid = threadIdx.x >> 6, lane = threadIdx.x & 63;
    int g = blockIdx.x & (NG8 - 1), gi = blockIdx.x >> 3;
    int ni = gi * 4 + wid;
    if (ni >= sz) return;
    int node = g * sz + ni;
    if (node >= n_nodes) return;
    int deg = min(cnt[node], CAP);
    int base = node << CAPSH;
    int q = lane >> 4, c = lane & 15;
    int mys = (lane < deg) ? (int)slots[base + lane] : 0;   // one coalesced 128B load
    int dmain = min(deg, 64);
    const uint2* P1v = (const uint2*)P1b;             // row = 16 uint2 (64 bf16)
    float a0=0.f,a1=0.f,a2=0.f,a3=0.f, b0=0.f,b1v=0.f,b2v=0.f,b3=0.f;
    float c0=0.f,c1=0.f,c2=0.f,c3=0.f, d0=0.f,d1=0.f,d2=0.f,d3=0.f;
    int i = 0;
    for (; i + 16 <= dmain; i += 16) {                // full wave active: shfl safe
        int sA = __shfl(mys, i + q, 64);
        int sB = __shfl(mys, i + 4 + q, 64);
        int sC = __shfl(mys, i + 8 + q, 64);
        int sD = __shfl(mys, i + 12 + q, 64);
        uint2 uA = P1v[(sA << 4) + c];
        uint2 uB = P1v[(sB << 4) + c];
        uint2 uC = P1v[(sC << 4) + c];
        uint2 uD = P1v[(sD << 4) + c];
        a0 += blo(uA.x); a1 += bhi(uA.x); a2 += blo(uA.y); a3 += bhi(uA.y);
        b0 += blo(uB.x); b1v += bhi(uB.x); b2v += blo(uB.y); b3 += bhi(uB.y);
        c0 += blo(uC.x); c1 += bhi(uC.x); c2 += blo(uC.y); c3 += bhi(uC.y);
        d0 += blo(uD.x); d1 += bhi(uD.x); d2 += blo(uD.y); d3 += bhi(uD.y);
    }
    for (; i + 4 <= dmain; i += 4) {                  // full wave active: shfl safe
        int sA = __shfl(mys, i + q, 64);
        uint2 uA = P1v[(sA << 4) + c];
        a0 += blo(uA.x); a1 += bhi(uA.x); a2 += blo(uA.y); a3 += bhi(uA.y);
    }
    {   // partial last group: shfl HOISTED above the divergent guard
        int sA = __shfl(mys, i + q, 64);
        if (q < dmain - i) {
            uint2 uA = P1v[(sA << 4) + c];
            a0 += blo(uA.x); a1 += bhi(uA.x); a2 += blo(uA.y); a3 += bhi(uA.y);
        }
    }
    for (int j = 64 + q; j < deg; j += 4) {           // rare deg>64 tail, direct loads
        int sA = slots[base + j];
        uint2 uA = P1v[(sA << 4) + c];
        a0 += blo(uA.x); a1 += bhi(uA.x); a2 += blo(uA.y); a3 += bhi(uA.y);
    }
    a0 += b0 + c0 + d0; a1 += b1v + c1 + d1; a2 += b2v + c2 + d2; a3 += b3 + c3 + d3;
    a0 += __shfl_xor(a0, 16, 64); a0 += __shfl_xor(a0, 32, 64);
    a1 += __shfl_xor(a1, 16, 64); a1 += __shfl_xor(a1, 32, 64);
    a2 += __shfl_xor(a2, 16, 64); a2 += __shfl_xor(a2, 32, 64);
    a3 += __shfl_xor(a3, 16, 64); a3 += __shfl_xor(a3, 32, 64);
    if (q == 0) {
        float4 bb = *(const float4*)(b1 + 4 * c);
        float4 v;
        v.x = fmaxf(a0 + bb.x, 0.f);
        v.y = fmaxf(a1 + bb.y, 0.f);
        v.z = fmaxf(a2 + bb.z, 0.f);
        v.w = fmaxf(a3 + bb.w, 0.f);
        *(float4*)&arow[wid][4 * c] = v;
    }
    // wave-local LDS bounce (in-order within wave)
    int half = lane >> 5, c32 = lane & 31, kb = half * 32;
    float acc2 = 0.f;
#pragma unroll
    for (int k = 0; k < 32; ++k) acc2 += arow[wid][kb + k] * w2s[(kb + k) * H2 + c32];
    acc2 += __shfl_xor(acc2, 32, 64);
    if (lane < 32) P2b[(size_t)node * H2 + c32] = f2b(acc2);
}

// ---- K4: agg2 + bias -> out (r14 verbatim: 1 node/wave) ----
__launch_bounds__(256)
__global__ void agg2_kernel(const unsigned short* __restrict__ P2b,
                            const int* __restrict__ cnt, const unsigned short* __restrict__ slots,
                            const float* __restrict__ b2, float* __restrict__ out,
                            int n_nodes, int sz) {
    int wid = threadIdx.x >> 6, lane = threadIdx.x & 63;
    int g = blockIdx.x & (NG8 - 1), gi = blockIdx.x >> 3;
    int ni = gi * 4 + wid;
    if (ni >= sz) return;
    int node = g * sz + ni;
    if (node >= n_nodes) return;
    int deg = min(cnt[node], CAP);
    int base = node << CAPSH;
    int o = lane >> 3, c = lane & 7;
    int mys = (lane < deg) ? (int)slots[base + lane] : 0;   // one coalesced load
    int dmain = min(deg, 64);
    const uint2* P2v = (const uint2*)P2b;             // row = 8 uint2 (32 bf16)
    float a0=0.f,a1=0.f,a2=0.f,a3=0.f, b0=0.f,b1v=0.f,b2v=0.f,b3=0.f;
    float c0=0.f,c1=0.f,c2=0.f,c3=0.f, d0=0.f,d1=0.f,d2=0.f,d3=0.f;
    int i = 0;
    for (; i + 32 <= dmain; i += 32) {                // full wave active: shfl safe
        int sA = __shfl(mys, i + o, 64);
        int sB = __shfl(mys, i + 8 + o, 64);
        int sC = __shfl(mys, i + 16 + o, 64);
        int sD = __shfl(mys, i + 24 + o, 64);
        uint2 uA = P2v[(sA << 3) + c];
        uint2 uB = P2v[(sB << 3) + c];
        uint2 uC = P2v[(sC << 3) + c];
        uint2 uD = P2v[(sD << 3) + c];
        a0 += blo(uA.x); a1 += bhi(uA.x); a2 += blo(uA.y); a3 += bhi(uA.y);
        b0 += blo(uB.x); b1v += bhi(uB.x); b2v += blo(uB.y); b3 += bhi(uB.y);
        c0 += blo(uC.x); c1 += bhi(uC.x); c2 += blo(uC.y); c3 += bhi(uC.y);
        d0 += blo(uD.x); d1 += bhi(uD.x); d2 += blo(uD.y); d3 += bhi(uD.y);
    }
    for (; i + 8 <= dmain; i += 8) {                  // full wave active: shfl safe
        int sA = __shfl(mys, i + o, 64);
        uint2 uA = P2v[(sA << 3) + c];
        a0 += blo(uA.x); a1 += bhi(uA.x); a2 += blo(uA.y); a3 += bhi(uA.y);
    }
    {   // partial last group: shfl HOISTED above the divergent guard
        int sA = __shfl(mys, i + o, 64);
        if (o < dmain - i) {
            uint2 uA = P2v[(sA << 3) + c];
            a0 += blo(uA.x); a1 += bhi(uA.x); a2 += blo(uA.y); a3 += bhi(uA.y);
        }
    }
    for (int j = 64 + o; j < deg; j += 8) {           // rare deg>64 tail
        int sA = slots[base + j];
        uint2 uA = P2v[(sA << 3) + c];
        a0 += blo(uA.x); a1 += bhi(uA.x); a2 += blo(uA.y); a3 += bhi(uA.y);
    }
    a0 += b0 + c0 + d0; a1 += b1v + c1 + d1; a2 += b2v + c2 + d2; a3 += b3 + c3 + d3;
    a0 += __shfl_xor(a0, 8, 64); a0 += __shfl_xor(a0, 16, 64); a0 += __shfl_xor(a0, 32, 64);
    a1 += __shfl_xor(a1, 8, 64); a1 += __shfl_xor(a1, 16, 64); a1 += __shfl_xor(a1, 32, 64);
    a2 += __shfl_xor(a2, 8, 64); a2 += __shfl_xor(a2, 16, 64); a2 += __shfl_xor(a2, 32, 64);
    a3 += __shfl_xor(a3, 8, 64); a3 += __shfl_xor(a3, 16, 64); a3 += __shfl_xor(a3, 32, 64);
    if (o == 0) {
        float4 bb = *(const float4*)(b2 + 4 * c);
        float4 v;
        v.x = a0 + bb.x; v.y = a1 + bb.y; v.z = a2 + bb.z; v.w = a3 + bb.w;
        *(float4*)(out + (size_t)node * H2 + 4 * c) = v;
    }
}

extern "C" void kernel_launch(void* const* d_in, const int* in_sizes, int n_in,
                              void* d_out, int out_size, void* d_ws, size_t ws_size,
                              hipStream_t stream) {
    const float* F  = (const float*)d_in[0];
    const float* W1 = (const float*)d_in[1];
    const float* b1 = (const float*)d_in[2];
    const float* W2 = (const float*)d_in[3];
    const float* b2 = (const float*)d_in[4];
    const int* src  = (const int*)d_in[5];
    const int* dst  = (const int*)d_in[6];
    float* out = (float*)d_out;

    int n_nodes = in_sizes[0] / NF;                       // 20000
    int n_edges = in_sizes[5];                            // 640000
    int sz = (n_nodes + NG8 - 1) / NG8;                   // nodes per group (2500)
    unsigned inv_sz = (unsigned)(((1ULL << 32) + sz - 1) / (unsigned)sz);
    int nsb = (n_edges + SCHUNK - 1) / SCHUNK;            // stage blocks (625)

    // Workspace layout (~11.6 MB):
    unsigned short* P1b = (unsigned short*)d_ws;              // [n][64] bf16   2.56 MB
    unsigned short* P2b = P1b + (size_t)n_nodes * H1;         // [n][32] bf16   1.28 MB
    unsigned short* slots = P2b + (size_t)n_nodes * H2;       // [n][CAP]       5.12 MB
    int* cnt = (int*)(slots + ((size_t)n_nodes << CAPSH));    // [n]            80 KB
    unsigned* staged = (unsigned*)(cnt + n_nodes);            // [nsb][1024]    2.56 MB
    int* bofs = (int*)(staged + (size_t)nsb * SCHUNK);        // [9][nsb]       22.5 KB

    int g1 = nsb + (n_nodes + 31) / 32;                       // 625 + 625
    k1_kernel<<<g1, 256, 0, stream>>>(F, W1, src, dst, staged, bofs, P1b, cnt,
                                      inv_sz, n_nodes, n_edges, nsb);
    fill2_kernel<<<FILL_BPG * NG8, 256, 0, stream>>>(staged, bofs, cnt, slots, nsb);
    int bpg = (sz + 3) / 4;                                   // 4 nodes per block
    agg1gemm2_kernel<<<bpg * NG8, 256, 0, stream>>>(P1b, cnt, slots, b1, W2, P2b, n_nodes, sz);
    agg2_kernel<<<bpg * NG8, 256, 0, stream>>>(P2b, cnt, slots, b2, out, n_nodes, sz);
}

// Round 17
// 82.185 us; speedup vs baseline: 1.1182x; 1.0035x over previous
//
#include <hip/hip_runtime.h>

// GCN: out = agg(relu(agg(F)@W1 + b1)) @ W2 + b2
// Reordered (agg linear): P1 = F@W1 (bf16); A1 = b1 + agg(P1); P2 = relu(A1)@W2 (bf16);
//                         out = b2 + agg(P2)
// r16 skeleton; ONE delta: k1 gemm role 32 -> 16 rows/block (gemm blocks 625 -> 1250,
// grid 1250 -> 1875; per-wave 4 rows; shbuf 16KB -> 8KB). Applies r15's lesson (these
// latency-bound kernels hide latency via TLP across blocks, not per-wave depth) to k1,
// whose r13 PMC showed 21.7% occupancy (CUs underfilled at 4.9 blocks/CU).
// Lessons kept: no grid.sync (r7), no per-window compaction (r8), XCD-local slot
// writes (r4), ballot histogram (r10), shfl outside divergent guards (r13),
// coalesced LDS-staged F (r14), 1 node/wave aggs + max grid (r15).

#define NF 128
#define H1 64
#define H2 32
#define CAP 128       // slot capacity/node; deg ~ Poisson(32), P(>128) ~ 1e-30; guarded
#define CAPSH 7
#define NG8 8         // node-range groups (== XCDs)
#define SCHUNK 1024   // edges per stage block
#define FILL_BPG 160  // fill2 blocks per group

__device__ __forceinline__ float blo(unsigned u){ return __uint_as_float(u << 16); }
__device__ __forceinline__ float bhi(unsigned u){ return __uint_as_float(u & 0xffff0000u); }
__device__ __forceinline__ unsigned short f2b(float f){   // fp32 -> bf16 RNE
    unsigned x = __float_as_uint(f);
    return (unsigned short)((x + 0x7fffu + ((x >> 16) & 1u)) >> 16);
}

// ---- K1: stage blocks (bid < nsb) + gemm1 blocks (bid >= nsb, 16 rows each) ----
__launch_bounds__(256)
__global__ void k1_kernel(const float* __restrict__ F, const float* __restrict__ W1,
                          const int* __restrict__ src, const int* __restrict__ dst,
                          unsigned* __restrict__ staged, int* __restrict__ bofs,
                          unsigned short* __restrict__ P1b, int* __restrict__ cnt,
                          unsigned inv_sz, int n_nodes, int n_edges, int nsb) {
    __shared__ __align__(16) float shbuf[4][4][NF];   // 8 KB: frow (gemm) / sorted (stage)
    __shared__ int wcnt[4][NG8];
    __shared__ int wbase[4][NG8];
    __shared__ int bb0[NG8 + 1];
    const int t = threadIdx.x;
    const int bid = blockIdx.x;
    const int wid = t >> 6, lane = t & 63;

    if (bid < nsb) {
        // ---------- stage role (r16 verbatim): sort 1024-edge chunk by group ----------
        unsigned* sorted = (unsigned*)&shbuf[0][0][0];     // first 4 KB
        int e0 = bid * SCHUNK;
        int ce = min(n_edges - e0, SCHUNK);
        int i4 = e0 + t * 4;
        int dd[4], ss[4], bb[4], pp[4];
        bool val[4];
        if (i4 + 4 <= n_edges) {
            int4 d4 = *(const int4*)(dst + i4);
            int4 s4 = *(const int4*)(src + i4);
            dd[0]=d4.x; dd[1]=d4.y; dd[2]=d4.z; dd[3]=d4.w;
            ss[0]=s4.x; ss[1]=s4.y; ss[2]=s4.z; ss[3]=s4.w;
        } else {
#pragma unroll
            for (int k = 0; k < 4; ++k) {
                int e = i4 + k;
                dd[k] = (e < n_edges) ? dst[e] : -1;
                ss[k] = (e < n_edges) ? src[e] : 0;
            }
        }
        unsigned long long lt = (1ULL << lane) - 1ULL;
#pragma unroll
        for (int k = 0; k < 4; ++k) {
            val[k] = dd[k] >= 0;
            bb[k] = val[k]
                ? (int)(unsigned)(((unsigned long long)(unsigned)dd[k] * inv_sz) >> 32)
                : 0;
        }
#pragma unroll
        for (int b = 0; b < NG8; ++b) {
            int running = 0;
#pragma unroll
            for (int k = 0; k < 4; ++k) {
                unsigned long long m = __ballot(val[k] && (bb[k] == b));
                if (val[k] && (bb[k] == b)) pp[k] = running + (int)__popcll(m & lt);
                running += (int)__popcll(m);
            }
            if (lane == 0) wcnt[wid][b] = running;
        }
        __syncthreads();
        if (t < NG8) {
            int tot = 0;
#pragma unroll
            for (int w = 0; w < 4; ++w) { wbase[w][t] = tot; tot += wcnt[w][t]; }
            bb0[t] = tot;
        }
        __syncthreads();
        if (t == 0) {
            int run = 0;
#pragma unroll
            for (int b = 0; b < NG8; ++b) { int c = bb0[b]; bb0[b] = run; run += c; }
            bb0[NG8] = run;
        }
        __syncthreads();
#pragma unroll
        for (int k = 0; k < 4; ++k)
            if (val[k])
                sorted[bb0[bb[k]] + wbase[wid][bb[k]] + pp[k]] =
                    ((unsigned)dd[k] << 16) | (unsigned)ss[k];
        __syncthreads();
        for (int j = t; j < ce; j += 256) staged[(size_t)bid * SCHUNK + j] = sorted[j];
        if (t < NG8 + 1) bofs[t * nsb + bid] = bb0[t];
        return;
    }

    // ---------- gemm1 role: zero cnt; P1b = F @ W1; 16 rows/block (4/wave) ----------
    int gb = bid - nsb;
    int zi = gb * 256 + t;
    if (zi < n_nodes) cnt[zi] = 0;
    int row0 = gb * 16 + wid * 4;
    {
        const float4* F4 = (const float4*)F;              // row stride = 32 float4
        float4 tmp[2];
#pragma unroll
        for (int j = 0; j < 2; ++j) {
            int flat = j * 64 + lane;                     // [0,128): 4 rows x 32 f4
            int r = flat >> 5, c4 = flat & 31;
            int row = row0 + r;
            int rc = min(row, n_nodes - 1);               // clamp reads; stores guarded
            tmp[j] = F4[(size_t)rc * 32 + c4];
        }
#pragma unroll
        for (int j = 0; j < 2; ++j) {
            int flat = j * 64 + lane;
            int r = flat >> 5, c4 = flat & 31;
            *(float4*)&shbuf[wid][r][c4 * 4] = tmp[j];
        }
    }
    float acc[4] = {0.f, 0.f, 0.f, 0.f};
#pragma unroll 1
    for (int cc = 0; cc < 2; ++cc) {             // two 64-k chunks (caps VGPR use)
        float wreg[64];                          // my column's 64 weights, in registers
#pragma unroll
        for (int k = 0; k < 64; ++k) wreg[k] = W1[(cc * 64 + k) * H1 + lane];
#pragma unroll
        for (int r = 0; r < 4; ++r) {
            const float4* fr = (const float4*)&shbuf[wid][r][cc * 64];
#pragma unroll
            for (int k4 = 0; k4 < 16; ++k4) {
                float4 fv = fr[k4];              // LDS broadcast read (same addr/wave)
                acc[r] += fv.x * wreg[k4 * 4 + 0] + fv.y * wreg[k4 * 4 + 1]
                        + fv.z * wreg[k4 * 4 + 2] + fv.w * wreg[k4 * 4 + 3];
            }
        }
    }
#pragma unroll
    for (int r = 0; r < 4; ++r) {
        int row = row0 + r;
        if (row < n_nodes) P1b[(size_t)row * H1 + lane] = f2b(acc[r]);
    }
}

// ---- K2: fill2 (r16 verbatim) ----
__launch_bounds__(256)
__global__ void fill2_kernel(const unsigned* __restrict__ staged, const int* __restrict__ bofs,
                             int* __restrict__ cnt, unsigned short* __restrict__ slots,
                             int nsb) {
    int g = blockIdx.x & (NG8 - 1), gi = blockIdx.x >> 3;
    for (int sb = gi; sb < nsb; sb += FILL_BPG) {
        int st = bofs[g * nsb + sb];
        int en = bofs[(g + 1) * nsb + sb];
        const unsigned* seg = staged + (size_t)sb * SCHUNK;
        for (int j = st + threadIdx.x; j < en; j += 256) {
            unsigned u = seg[j];
            int d = u >> 16;
            int p = atomicAdd(&cnt[d], 1);
            if (p < CAP) slots[(d << CAPSH) + p] = (unsigned short)(u & 0xffffu);
        }
    }
}

// ---- K3: agg1 + bias + relu + gemm2 -> P2b (r16 verbatim: 1 node/wave) ----
__launch_bounds__(256)
__global__ void agg1gemm2_kernel(const unsigned short* __restrict__ P1b,
                                 const int* __restrict__ cnt, const unsigned short* __restrict__ slots,
                                 const float* __restrict__ b1, const float* __restrict__ W2,
                                 unsigned short* __restrict__ P2b, int n_nodes, int sz) {
    __shared__ float w2s[H1 * H2];   // 8 KB
    __shared__ float arow[4][H1];    // 1 KB
    {
        const float4* w4 = (const float4*)W2;
        float4* ws4 = (float4*)w2s;
#pragma unroll
        for (int j = 0; j < 2; ++j) ws4[threadIdx.x + 256 * j] = w4[threadIdx.x + 256 * j];
    }
    __syncthreads();
    int wid = threadIdx.x >> 6, lane = threadIdx.x & 63;
    int g = blockIdx.x & (NG8 - 1), gi = blockIdx.x >> 3;
    int ni = gi * 4 + wid;
    if (ni >= sz) return;
    int node = g * sz + ni;
    if (node >= n_nodes) return;
    int deg = min(cnt[node], CAP);
    int base = node << CAPSH;
    int q = lane >> 4, c = lane & 15;
    int mys = (lane < deg) ? (int)slots[base + lane] : 0;   // one coalesced 128B load
    int dmain = min(deg, 64);
    const uint2* P1v = (const uint2*)P1b;             // row = 16 uint2 (64 bf16)
    float a0=0.f,a1=0.f,a2=0.f,a3=0.f, b0=0.f,b1v=0.f,b2v=0.f,b3=0.f;
    float c0=0.f,c1=0.f,c2=0.f,c3=0.f, d0=0.f,d1=0.f,d2=0.f,d3=0.f;
    int i = 0;
    for (; i + 16 <= dmain; i += 16) {                // full wave active: shfl safe
        int sA = __shfl(mys, i + q, 64);
        int sB = __shfl(mys, i + 4 + q, 64);
        int sC = __shfl(mys, i + 8 + q, 64);
        int sD = __shfl(mys, i + 12 + q, 64);
        uint2 uA = P1v[(sA << 4) + c];
        uint2 uB = P1v[(sB << 4) + c];
        uint2 uC = P1v[(sC << 4) + c];
        uint2 uD = P1v[(sD << 4) + c];
        a0 += blo(uA.x); a1 += bhi(uA.x); a2 += blo(uA.y); a3 += bhi(uA.y);
        b0 += blo(uB.x); b1v += bhi(uB.x); b2v += blo(uB.y); b3 += bhi(uB.y);
        c0 += blo(uC.x); c1 += bhi(uC.x); c2 += blo(uC.y); c3 += bhi(uC.y);
        d0 += blo(uD.x); d1 += bhi(uD.x); d2 += blo(uD.y); d3 += bhi(uD.y);
    }
    for (; i + 4 <= dmain; i += 4) {                  // full wave active: shfl safe
        int sA = __shfl(mys, i + q, 64);
        uint2 uA = P1v[(sA << 4) + c];
        a0 += blo(uA.x); a1 += bhi(uA.x); a2 += blo(uA.y); a3 += bhi(uA.y);
    }
    {   // partial last group: shfl HOISTED above the divergent guard
        int sA = __shfl(mys, i + q, 64);
        if (q < dmain - i) {
            uint2 uA = P1v[(sA << 4) + c];
            a0 += blo(uA.x); a1 += bhi(uA.x); a2 += blo(uA.y); a3 += bhi(uA.y);
        }
    }
    for (int j = 64 + q; j < deg; j += 4) {           // rare deg>64 tail, direct loads
        int sA = slots[base + j];
        uint2 uA = P1v[(sA << 4) + c];
        a0 += blo(uA.x); a1 += bhi(uA.x); a2 += blo(uA.y); a3 += bhi(uA.y);
    }
    a0 += b0 + c0 + d0; a1 += b1v + c1 + d1; a2 += b2v + c2 + d2; a3 += b3 + c3 + d3;
    a0 += __shfl_xor(a0, 16, 64); a0 += __shfl_xor(a0, 32, 64);
    a1 += __shfl_xor(a1, 16, 64); a1 += __shfl_xor(a1, 32, 64);
    a2 += __shfl_xor(a2, 16, 64); a2 += __shfl_xor(a2, 32, 64);
    a3 += __shfl_xor(a3, 16, 64); a3 += __shfl_xor(a3, 32, 64);
    if (q == 0) {
        float4 bb = *(const float4*)(b1 + 4 * c);
        float4 v;
        v.x = fmaxf(a0 + bb.x, 0.f);
        v.y = fmaxf(a1 + bb.y, 0.f);
        v.z = fmaxf(a2 + bb.z, 0.f);
        v.w = fmaxf(a3 + bb.w, 0.f);
        *(float4*)&arow[wid][4 * c] = v;
    }
    // wave-local LDS bounce (in-order within wave)
    int half = lane >> 5, c32 = lane & 31, kb = half * 32;
    float acc2 = 0.f;
#pragma unroll
    for (int k = 0; k < 32; ++k) acc2 += arow[wid][kb + k] * w2s[(kb + k) * H2 + c32];
    acc2 += __shfl_xor(acc2, 32, 64);
    if (lane < 32) P2b[(size_t)node * H2 + c32] = f2b(acc2);
}

// ---- K4: agg2 + bias -> out (r16 verbatim: 1 node/wave) ----
__launch_bounds__(256)
__global__ void agg2_kernel(const unsigned short* __restrict__ P2b,
                            const int* __restrict__ cnt, const unsigned short* __restrict__ slots,
                            const float* __restrict__ b2, float* __restrict__ out,
                            int n_nodes, int sz) {
    int wid = threadIdx.x >> 6, lane = threadIdx.x & 63;
    int g = blockIdx.x & (NG8 - 1), gi = blockIdx.x >> 3;
    int ni = gi * 4 + wid;
    if (ni >= sz) return;
    int node = g * sz + ni;
    if (node >= n_nodes) return;
    int deg = min(cnt[node], CAP);
    int base = node << CAPSH;
    int o = lane >> 3, c = lane & 7;
    int mys = (lane < deg) ? (int)slots[base + lane] : 0;   // one coalesced load
    int dmain = min(deg, 64);
    const uint2* P2v = (const uint2*)P2b;             // row = 8 uint2 (32 bf16)
    float a0=0.f,a1=0.f,a2=0.f,a3=0.f, b0=0.f,b1v=0.f,b2v=0.f,b3=0.f;
    float c0=0.f,c1=0.f,c2=0.f,c3=0.f, d0=0.f,d1=0.f,d2=0.f,d3=0.f;
    int i = 0;
    for (; i + 32 <= dmain; i += 32) {                // full wave active: shfl safe
        int sA = __shfl(mys, i + o, 64);
        int sB = __shfl(mys, i + 8 + o, 64);
        int sC = __shfl(mys, i + 16 + o, 64);
        int sD = __shfl(mys, i + 24 + o, 64);
        uint2 uA = P2v[(sA << 3) + c];
        uint2 uB = P2v[(sB << 3) + c];
        uint2 uC = P2v[(sC << 3) + c];
        uint2 uD = P2v[(sD << 3) + c];
        a0 += blo(uA.x); a1 += bhi(uA.x); a2 += blo(uA.y); a3 += bhi(uA.y);
        b0 += blo(uB.x); b1v += bhi(uB.x); b2v += blo(uB.y); b3 += bhi(uB.y);
        c0 += blo(uC.x); c1 += bhi(uC.x); c2 += blo(uC.y); c3 += bhi(uC.y);
        d0 += blo(uD.x); d1 += bhi(uD.x); d2 += blo(uD.y); d3 += bhi(uD.y);
    }
    for (; i + 8 <= dmain; i += 8) {                  // full wave active: shfl safe
        int sA = __shfl(mys, i + o, 64);
        uint2 uA = P2v[(sA << 3) + c];
        a0 += blo(uA.x); a1 += bhi(uA.x); a2 += blo(uA.y); a3 += bhi(uA.y);
    }
    {   // partial last group: shfl HOISTED above the divergent guard
        int sA = __shfl(mys, i + o, 64);
        if (o < dmain - i) {
            uint2 uA = P2v[(sA << 3) + c];
            a0 += blo(uA.x); a1 += bhi(uA.x); a2 += blo(uA.y); a3 += bhi(uA.y);
        }
    }
    for (int j = 64 + o; j < deg; j += 8) {           // rare deg>64 tail
        int sA = slots[base + j];
        uint2 uA = P2v[(sA << 3) + c];
        a0 += blo(uA.x); a1 += bhi(uA.x); a2 += blo(uA.y); a3 += bhi(uA.y);
    }
    a0 += b0 + c0 + d0; a1 += b1v + c1 + d1; a2 += b2v + c2 + d2; a3 += b3 + c3 + d3;
    a0 += __shfl_xor(a0, 8, 64); a0 += __shfl_xor(a0, 16, 64); a0 += __shfl_xor(a0, 32, 64);
    a1 += __shfl_xor(a1, 8, 64); a1 += __shfl_xor(a1, 16, 64); a1 += __shfl_xor(a1, 32, 64);
    a2 += __shfl_xor(a2, 8, 64); a2 += __shfl_xor(a2, 16, 64); a2 += __shfl_xor(a2, 32, 64);
    a3 += __shfl_xor(a3, 8, 64); a3 += __shfl_xor(a3, 16, 64); a3 += __shfl_xor(a3, 32, 64);
    if (o == 0) {
        float4 bb = *(const float4*)(b2 + 4 * c);
        float4 v;
        v.x = a0 + bb.x; v.y = a1 + bb.y; v.z = a2 + bb.z; v.w = a3 + bb.w;
        *(float4*)(out + (size_t)node * H2 + 4 * c) = v;
    }
}

extern "C" void kernel_launch(void* const* d_in, const int* in_sizes, int n_in,
                              void* d_out, int out_size, void* d_ws, size_t ws_size,
                              hipStream_t stream) {
    const float* F  = (const float*)d_in[0];
    const float* W1 = (const float*)d_in[1];
    const float* b1 = (const float*)d_in[2];
    const float* W2 = (const float*)d_in[3];
    const float* b2 = (const float*)d_in[4];
    const int* src  = (const int*)d_in[5];
    const int* dst  = (const int*)d_in[6];
    float* out = (float*)d_out;

    int n_nodes = in_sizes[0] / NF;                       // 20000
    int n_edges = in_sizes[5];                            // 640000
    int sz = (n_nodes + NG8 - 1) / NG8;                   // nodes per group (2500)
    unsigned inv_sz = (unsigned)(((1ULL << 32) + sz - 1) / (unsigned)sz);
    int nsb = (n_edges + SCHUNK - 1) / SCHUNK;            // stage blocks (625)

    // Workspace layout (~11.6 MB):
    unsigned short* P1b = (unsigned short*)d_ws;              // [n][64] bf16   2.56 MB
    unsigned short* P2b = P1b + (size_t)n_nodes * H1;         // [n][32] bf16   1.28 MB
    unsigned short* slots = P2b + (size_t)n_nodes * H2;       // [n][CAP]       5.12 MB
    int* cnt = (int*)(slots + ((size_t)n_nodes << CAPSH));    // [n]            80 KB
    unsigned* staged = (unsigned*)(cnt + n_nodes);            // [nsb][1024]    2.56 MB
    int* bofs = (int*)(staged + (size_t)nsb * SCHUNK);        // [9][nsb]       22.5 KB

    int g1 = nsb + (n_nodes + 15) / 16;                       // 625 + 1250 = 1875
    k1_kernel<<<g1, 256, 0, stream>>>(F, W1, src, dst, staged, bofs, P1b, cnt,
                                      inv_sz, n_nodes, n_edges, nsb);
    fill2_kernel<<<FILL_BPG * NG8, 256, 0, stream>>>(staged, bofs, cnt, slots, nsb);
    int bpg = (sz + 3) / 4;                                   // 4 nodes per block
    agg1gemm2_kernel<<<bpg * NG8, 256, 0, stream>>>(P1b, cnt, slots, b1, W2, P2b, n_nodes, sz);
    agg2_kernel<<<bpg * NG8, 256, 0, stream>>>(P2b, cnt, slots, b2, out, n_nodes, sz);
}